// Round 1
// baseline (1250.381 us; speedup 1.0000x reference)
//
#include <hip/hip_runtime.h>
#include <cstddef>

#define LL 64
#define NN 4096
#define BB 128

// folded index n -> lattice site (row*64+col), closed form of the reference PERM
__device__ __forceinline__ int perm_site(int n) {
    if (n == 0) return 0;
    int j = (31 - __clz(n)) >> 1;      // level: n in [4^j, 4*4^j)
    int g = n >> (2 * j);              // sublattice 1..3
    int o = n - (g << (2 * j));        // offset within slice
    int side = 1 << j;                 // slice is side x side, row-major
    int rr = o >> j, cc = o & (side - 1);
    int i = 5 - j;                     // scale index of reference loop
    int s = 1 << i;
    int p = 1 << (i + 1);
    int r, c;
    if (g == 1)      { r = s + rr * p; c = s + cc * p; }
    else if (g == 2) { r = s + rr * p; c = cc * p;     }
    else             { r = rr * p;     c = s + cc * p; }
    return r * LL + c;
}

// visible-prefix limits for folded row r: exclusive = S, inclusive = E
__device__ __forceinline__ void klims(int r, int& S, int& E) {
    if (r == 0) { S = 0; E = 1; return; }
    int j = (31 - __clz(r)) >> 1;
    int g = r >> (2 * j);
    S = g << (2 * j);
    E = (g + 1) << (2 * j);
}

// xf[n][b] = x[b][perm(n)]  (store folded input transposed: [N, B])
__global__ void fold_kernel(const float* __restrict__ x, float* __restrict__ xf) {
    int gid = blockIdx.x * blockDim.x + threadIdx.x;   // N*B threads
    int n = gid >> 7;
    int b = gid & 127;
    xf[n * BB + b] = x[b * NN + perm_site(n)];
}

// Masked GEMM: out[R][b] = act( sum_k A[k][b] * W[R][k] over masked prefix + bias[R] )
// A: [SEGS*NN, BB] (k-major, transposed activations), W: [M, SEGS*NN] row-major.
// Mask: per channel-block of N columns, row r=R&(NN-1) sees k in [0, klim(r)).
// MODE 0: prelu -> out [M, BB].  MODE 1: sigmoid + unfold scatter -> out [BB, NN].
template <int SEGS, bool EXCL, int MODE>
__global__ __launch_bounds__(256) void made_gemm(
        const float* __restrict__ A,
        const float* __restrict__ W,
        const float* __restrict__ bias,
        const float* __restrict__ alpha,
        float* __restrict__ out) {
    constexpr int KT = 32, MT = 32;
    constexpr int Ktot = SEGS * NN;
    __shared__ float As[KT][BB + 4];   // [k][b]
    __shared__ float Wt[KT][MT + 4];   // [k][m]
    const int tid = threadIdx.x;
    const int tx = tid & 31;           // batch quad index (b = tx*4+j)
    const int my = tid >> 5;           // col quad index (m = my*4+i)
    const int R0 = blockIdx.x * MT;
    const int r0 = R0 & (NN - 1);

    int klim[4];
#pragma unroll
    for (int i = 0; i < 4; ++i) {
        int S, E;
        klims(r0 + my * 4 + i, S, E);
        klim[i] = EXCL ? S : E;
    }
    int Smax, Emax;
    klims(r0 + MT - 1, Smax, Emax);            // klim monotone in r
    const int kmax = EXCL ? Smax : Emax;
    const int nkt = (kmax + KT - 1) / KT;      // tiles per segment
    const bool uniform = (r0 >= 64);           // whole tile in one level-group

    float acc[4][4] = {};

    const int lm = tid >> 3, lu = tid & 7;     // W-load mapping
    float4 pa[4];                              // prefetch regs
    float4 pw;

    const int ntiles = SEGS * nkt;

#define ISSUE_LOADS(T)                                                        \
    {                                                                         \
        int seg_ = (T) / nkt, kt_ = (T) - seg_ * nkt;                         \
        int kb_ = seg_ * NN + kt_ * KT;                                       \
        _Pragma("unroll")                                                     \
        for (int tt = 0; tt < 4; ++tt) {                                      \
            int idx = tt * 256 + tid;                                         \
            int kr = idx >> 5, qb = idx & 31;                                 \
            pa[tt] = *(const float4*)&A[(size_t)(kb_ + kr) * BB + qb * 4];    \
        }                                                                     \
        pw = *(const float4*)&W[(size_t)(R0 + lm) * Ktot + kb_ + lu * 4];     \
    }

    ISSUE_LOADS(0);
    for (int t = 0; t < ntiles; ++t) {
        __syncthreads();
#pragma unroll
        for (int tt = 0; tt < 4; ++tt) {
            int idx = tt * 256 + tid;
            int kr = idx >> 5, qb = idx & 31;
            *(float4*)&As[kr][qb * 4] = pa[tt];
        }
        Wt[lu * 4 + 0][lm] = pw.x;
        Wt[lu * 4 + 1][lm] = pw.y;
        Wt[lu * 4 + 2][lm] = pw.z;
        Wt[lu * 4 + 3][lm] = pw.w;
        __syncthreads();
        if (t + 1 < ntiles) ISSUE_LOADS(t + 1);

        const int kt = t - (t / nkt) * nkt;
        const int kloc0 = kt * KT;
        if (uniform) {
#pragma unroll
            for (int kk = 0; kk < KT; ++kk) {
                float4 a = *(const float4*)&As[kk][tx * 4];
                float4 w = *(const float4*)&Wt[kk][my * 4];
                acc[0][0] = fmaf(w.x, a.x, acc[0][0]);
                acc[0][1] = fmaf(w.x, a.y, acc[0][1]);
                acc[0][2] = fmaf(w.x, a.z, acc[0][2]);
                acc[0][3] = fmaf(w.x, a.w, acc[0][3]);
                acc[1][0] = fmaf(w.y, a.x, acc[1][0]);
                acc[1][1] = fmaf(w.y, a.y, acc[1][1]);
                acc[1][2] = fmaf(w.y, a.z, acc[1][2]);
                acc[1][3] = fmaf(w.y, a.w, acc[1][3]);
                acc[2][0] = fmaf(w.z, a.x, acc[2][0]);
                acc[2][1] = fmaf(w.z, a.y, acc[2][1]);
                acc[2][2] = fmaf(w.z, a.z, acc[2][2]);
                acc[2][3] = fmaf(w.z, a.w, acc[2][3]);
                acc[3][0] = fmaf(w.w, a.x, acc[3][0]);
                acc[3][1] = fmaf(w.w, a.y, acc[3][1]);
                acc[3][2] = fmaf(w.w, a.z, acc[3][2]);
                acc[3][3] = fmaf(w.w, a.w, acc[3][3]);
            }
        } else {
            // first 64 rows of a channel block: per-row K limits (tiny work)
#pragma unroll
            for (int kk = 0; kk < KT; ++kk) {
                int kg = kloc0 + kk;
                float4 a = *(const float4*)&As[kk][tx * 4];
                float4 w = *(const float4*)&Wt[kk][my * 4];
                float wi[4] = {w.x, w.y, w.z, w.w};
#pragma unroll
                for (int i = 0; i < 4; ++i) {
                    float we = (kg < klim[i]) ? wi[i] : 0.0f;
                    acc[i][0] = fmaf(we, a.x, acc[i][0]);
                    acc[i][1] = fmaf(we, a.y, acc[i][1]);
                    acc[i][2] = fmaf(we, a.z, acc[i][2]);
                    acc[i][3] = fmaf(we, a.w, acc[i][3]);
                }
            }
        }
        __syncthreads();
    }
#undef ISSUE_LOADS

    if (MODE == 0) {
#pragma unroll
        for (int i = 0; i < 4; ++i) {
            int R = R0 + my * 4 + i;
            float bv = bias[R];
            float al = alpha[R];
            float4 o;
            float v;
            v = acc[i][0] + bv; o.x = fmaxf(v, 0.0f) + al * fminf(v, 0.0f);
            v = acc[i][1] + bv; o.y = fmaxf(v, 0.0f) + al * fminf(v, 0.0f);
            v = acc[i][2] + bv; o.z = fmaxf(v, 0.0f) + al * fminf(v, 0.0f);
            v = acc[i][3] + bv; o.w = fmaxf(v, 0.0f) + al * fminf(v, 0.0f);
            *(float4*)&out[(size_t)R * BB + tx * 4] = o;
        }
    } else {
#pragma unroll
        for (int i = 0; i < 4; ++i) {
            int r = R0 + my * 4 + i;
            float bv = bias[r];
            int site = perm_site(r);
#pragma unroll
            for (int jj = 0; jj < 4; ++jj) {
                float v = acc[i][jj] + bv;
                float sv = 1.0f / (1.0f + __expf(-v));
                if (r == 0) sv = 0.5f;   // x_hat mask/bias at folded pos 0
                out[(size_t)(tx * 4 + jj) * NN + site] = sv;
            }
        }
    }
}

extern "C" void kernel_launch(void* const* d_in, const int* in_sizes, int n_in,
                              void* d_out, int out_size, void* d_ws, size_t ws_size,
                              hipStream_t stream) {
    const float* x  = (const float*)d_in[0];
    const float* W0 = (const float*)d_in[1];
    const float* b0 = (const float*)d_in[2];
    const float* a1 = (const float*)d_in[3];
    const float* W1 = (const float*)d_in[4];
    const float* b1 = (const float*)d_in[5];
    const float* a2 = (const float*)d_in[6];
    const float* W2 = (const float*)d_in[7];
    const float* b2 = (const float*)d_in[8];
    float* out = (float*)d_out;

    float* xf = (float*)d_ws;            // [4096, 128]  2 MB
    float* h0 = xf + (size_t)NN * BB;    // [8192, 128]  4 MB
    float* h1 = h0 + (size_t)2 * NN * BB;// [8192, 128]  4 MB

    fold_kernel<<<(NN * BB) / 256, 256, 0, stream>>>(x, xf);
    made_gemm<1, true, 0><<<2 * NN / 32, 256, 0, stream>>>(xf, W0, b0, a1, h0);
    made_gemm<2, false, 0><<<2 * NN / 32, 256, 0, stream>>>(h0, W1, b1, a2, h1);
    made_gemm<2, false, 1><<<NN / 32, 256, 0, stream>>>(h1, W2, b2, nullptr, out);
}

// Round 2
// 255.332 us; speedup vs baseline: 4.8971x; 4.8971x over previous
//
#include <hip/hip_runtime.h>
#include <hip/hip_bf16.h>
#include <cstddef>
#include <cstdint>

#define NN 4096
#define BB 128

using short8 = __attribute__((ext_vector_type(8))) short;
using f32x4  = __attribute__((ext_vector_type(4))) float;

// visible-prefix limits for folded row r: exclusive = S, inclusive = E
__device__ __forceinline__ void klims(int r, int& S, int& E) {
    if (r == 0) { S = 0; E = 1; return; }
    int j = (31 - __clz(r)) >> 1;
    int g = r >> (2 * j);
    S = g << (2 * j);
    E = (g + 1) << (2 * j);
}

// lattice site s -> folded index n (closed-form inverse of reference PERM)
__device__ __forceinline__ int inv_site(int s) {
    if (s == 0) return 0;
    int r = s >> 6, c = s & 63;
    int ir = r ? __builtin_ctz(r) : 6;
    int ic = c ? __builtin_ctz(c) : 6;
    int i = ir < ic ? ir : ic;
    int j = 5 - i;
    int rb = (r >> i) & 1, cb = (c >> i) & 1;
    int g = rb ? (cb ? 1 : 2) : 3;
    return (g << (2 * j)) + ((r >> (i + 1)) << j) + (c >> (i + 1));
}

// fragment-order element index for activation storage [k][b] (bf16)
// tile = 32k x 16b = 512 elems; within tile: lane=((k>>2)&3)*16+(b&15), j=((k>>4)&1)*4+(k&3)
__device__ __forceinline__ size_t fidx(int k, int b) {
    return (size_t)(((k >> 5) * 8 + (b >> 4)) * 512 + ((k >> 2) & 3) * 128 +
                    (b & 15) * 8 + ((k >> 4) & 1) * 4 + (k & 3));
}

__device__ __forceinline__ unsigned short f2bf(float f) {
    __hip_bfloat16 h = __float2bfloat16(f);
    return __builtin_bit_cast(unsigned short, h);
}

__device__ __forceinline__ void gload_lds16(const void* g, void* l) {
    __builtin_amdgcn_global_load_lds(
        (const __attribute__((address_space(1))) unsigned int*)g,
        (__attribute__((address_space(3))) unsigned int*)l, 16, 0, 0);
}

// fold: xf_frag[n][b] = x[b][site(n)] as bf16, coalesced reads over x
__global__ void fold_k(const float* __restrict__ x, unsigned short* __restrict__ xf) {
    int gid = blockIdx.x * 256 + threadIdx.x;  // b*4096 + s
    int b = gid >> 12, s = gid & 4095;
    float v = x[gid];
    int n = inv_site(s);
    xf[fidx(n, b)] = f2bf(v);
}

// final: out[b][s] = sigmoid(p0+p1+bias) with folded-pos-0 override
__global__ void reduce_k(const float* __restrict__ p, const float* __restrict__ b2,
                         float* __restrict__ out) {
    int gid = blockIdx.x * 256 + threadIdx.x;  // b*4096 + s
    int b = gid >> 12, s = gid & 4095;
    int n = inv_site(s);
    float v = p[(size_t)n * BB + b] + p[(size_t)NN * BB + (size_t)n * BB + b] + b2[n];
    float sg = 1.0f / (1.0f + __expf(-v));
    out[gid] = (n == 0) ? 0.5f : sg;
}

// Masked GEMM via bf16 MFMA. out[m][b] = act(sum_k W[m][k]*A[k][b] + bias)
// A: bf16 fragment-order buffer (fidx layout), W: fp32 row-major [M][Ktot].
// Per-channel-block prefix mask applied per element at W staging.
// MODE 0: prelu -> bf16 frag-order store.  MODE 1: fp32 partial (split-K by blockIdx.y).
template <bool EXCL, int MODE>
__global__ __launch_bounds__(256) void made_mfma(
        const char* __restrict__ A, const float* __restrict__ W,
        const float* __restrict__ bias, const float* __restrict__ alpha,
        void* __restrict__ outp, int M, int Ktot, int nseg) {
    __shared__ __align__(16) char smem[36864];  // A: 2x16KB, W: 2x2KB

    const int tid  = threadIdx.x;
    const int wid  = tid >> 6;
    const int lane = tid & 63;
    const int r0   = M - 16 - (int)blockIdx.x * 16;   // reversed: heavy tiles first
    const int r_ch = r0 & (NN - 1);
    const int seg0 = (MODE == 1) ? (int)blockIdx.y : 0;
    const int nsl  = (MODE == 1) ? 1 : nseg;

    // W staging role: row = tid>>4 (16 rows), 4 consecutive k at (tid&15)*4
    const int srow = tid >> 4;
    const int scol = tid & 15;
    int S, E;
    klims(r_ch + srow, S, E);
    const int kl = EXCL ? S : E;       // per-row seg-local prefix limit
    klims(r_ch + 15, S, E);
    const int kmax = EXCL ? S : E;     // tile max (klim monotone in r)
    const int nkt = (kmax + 63) >> 6;  // 64-wide k-steps per segment
    const int nt  = nsl * nkt;

    f32x4 acc[2] = {};
    float wreg[4];
    int stage_kb = 0;

#define STAGE_ISSUE(T, BUF)                                                     \
    {                                                                           \
        int sg_ = seg0 + (T) / nkt;                                             \
        int kb_ = ((T) % nkt) << 6;                                             \
        stage_kb = kb_;                                                         \
        const float* wp_ = &W[(size_t)(r0 + srow) * Ktot + sg_ * NN + kb_ + scol * 4]; \
        float4 wv_ = *(const float4*)wp_;                                       \
        wreg[0] = wv_.x; wreg[1] = wv_.y; wreg[2] = wv_.z; wreg[3] = wv_.w;     \
        const char* as_ = A + ((size_t)(sg_ * NN + kb_)) * 256 + wid * 4096 + lane * 16; \
        char* ad_ = smem + (BUF) * 16384 + wid * 4096;                          \
        _Pragma("unroll")                                                       \
        for (int it_ = 0; it_ < 4; ++it_)                                       \
            gload_lds16(as_ + it_ * 1024, ad_ + it_ * 1024);                    \
    }

#define STAGE_FINISH(BUF)                                                       \
    {                                                                           \
        ushort4 uw_;                                                            \
        uw_.x = f2bf((stage_kb + scol * 4 + 0 < kl) ? wreg[0] : 0.0f);          \
        uw_.y = f2bf((stage_kb + scol * 4 + 1 < kl) ? wreg[1] : 0.0f);          \
        uw_.z = f2bf((stage_kb + scol * 4 + 2 < kl) ? wreg[2] : 0.0f);          \
        uw_.w = f2bf((stage_kb + scol * 4 + 3 < kl) ? wreg[3] : 0.0f);          \
        int kk_ = scol >> 3, q_ = (scol >> 2) & 1;                              \
        int lp_ = (scol & 3) * 16 + srow;                                       \
        *(ushort4*)(smem + 32768 + (BUF) * 2048 + kk_ * 1024 + lp_ * 16 + q_ * 8) = uw_; \
    }

#define COMPUTE(BUF)                                                            \
    _Pragma("unroll")                                                           \
    for (int kk_ = 0; kk_ < 2; ++kk_) {                                         \
        short8 wf_ = *(const short8*)(smem + 32768 + (BUF) * 2048 + kk_ * 1024 + lane * 16); \
        _Pragma("unroll")                                                       \
        for (int q_ = 0; q_ < 2; ++q_) {                                        \
            int bq_ = wid * 2 + q_;                                             \
            short8 af_ = *(const short8*)(smem + (BUF) * 16384 + (kk_ * 8 + bq_) * 1024 + lane * 16); \
            acc[q_] = __builtin_amdgcn_mfma_f32_16x16x32_bf16(wf_, af_, acc[q_], 0, 0, 0); \
        }                                                                       \
    }

    STAGE_ISSUE(0, 0);
    STAGE_FINISH(0);
    __syncthreads();

    for (int t = 0; t < nt; ++t) {
        int buf = t & 1;
        if (t + 1 < nt) STAGE_ISSUE(t + 1, buf ^ 1);
        COMPUTE(buf);
        if (t + 1 < nt) {
            STAGE_FINISH(buf ^ 1);
            __syncthreads();
        }
    }

#undef STAGE_ISSUE
#undef STAGE_FINISH
#undef COMPUTE

    if (MODE == 0) {
        unsigned short* hout = (unsigned short*)outp;
#pragma unroll
        for (int i = 0; i < 4; ++i) {
            int m = r0 + (lane >> 4) * 4 + i;
            float bv = bias[m], av = alpha[m];
#pragma unroll
            for (int q = 0; q < 2; ++q) {
                int b = (wid * 2 + q) * 16 + (lane & 15);
                float v = acc[q][i] + bv;
                v = fmaxf(v, 0.0f) + av * fminf(v, 0.0f);
                hout[fidx(m, b)] = f2bf(v);
            }
        }
    } else {
        float* P = (float*)outp + (size_t)blockIdx.y * NN * BB;
#pragma unroll
        for (int i = 0; i < 4; ++i) {
            int m = r0 + (lane >> 4) * 4 + i;
#pragma unroll
            for (int q = 0; q < 2; ++q) {
                int b = (wid * 2 + q) * 16 + (lane & 15);
                P[(size_t)m * BB + b] = acc[q][i];
            }
        }
    }
}

extern "C" void kernel_launch(void* const* d_in, const int* in_sizes, int n_in,
                              void* d_out, int out_size, void* d_ws, size_t ws_size,
                              hipStream_t stream) {
    const float* x  = (const float*)d_in[0];
    const float* W0 = (const float*)d_in[1];
    const float* b0 = (const float*)d_in[2];
    const float* a1 = (const float*)d_in[3];
    const float* W1 = (const float*)d_in[4];
    const float* b1 = (const float*)d_in[5];
    const float* a2 = (const float*)d_in[6];
    const float* W2 = (const float*)d_in[7];
    const float* b2 = (const float*)d_in[8];

    char* ws = (char*)d_ws;
    unsigned short* xf = (unsigned short*)ws;                // 1 MB  (4096x128 bf16, frag order)
    unsigned short* h0 = (unsigned short*)(ws + (1 << 20));  // 2 MB  (8192x128)
    unsigned short* h1 = (unsigned short*)(ws + (3 << 20));  // 2 MB  (8192x128)
    float*          pp = (float*)(ws + (5 << 20));           // 4 MB  (2 x 4096x128 fp32 partials)

    fold_k<<<2048, 256, 0, stream>>>(x, xf);
    made_mfma<true, 0><<<512, 256, 0, stream>>>((const char*)xf, W0, b0, a1, h0, 2 * NN, NN, 1);
    made_mfma<false, 0><<<512, 256, 0, stream>>>((const char*)h0, W1, b1, a2, h1, 2 * NN, 2 * NN, 2);
    made_mfma<false, 1><<<dim3(256, 2), 256, 0, stream>>>((const char*)h1, W2, b2, nullptr, pp, NN, 2 * NN, 1);
    reduce_k<<<2048, 256, 0, stream>>>(pp, b2, (float*)d_out);
}

// Round 3
// 171.150 us; speedup vs baseline: 7.3057x; 1.4919x over previous
//
#include <hip/hip_runtime.h>
#include <hip/hip_bf16.h>
#include <cstddef>
#include <cstdint>

#define NN 4096
#define BB 128

using short8 = __attribute__((ext_vector_type(8))) short;
using f32x4  = __attribute__((ext_vector_type(4))) float;

// visible-prefix limits for folded row r: exclusive = S, inclusive = E
__device__ __forceinline__ void klims(int r, int& S, int& E) {
    if (r == 0) { S = 0; E = 1; return; }
    int j = (31 - __clz(r)) >> 1;
    int g = r >> (2 * j);
    S = g << (2 * j);
    E = (g + 1) << (2 * j);
}

// folded index n -> lattice site (row*64+col)
__device__ __forceinline__ int perm_site(int n) {
    if (n == 0) return 0;
    int j = (31 - __clz(n)) >> 1;
    int g = n >> (2 * j);
    int o = n - (g << (2 * j));
    int side = 1 << j;
    int rr = o >> j, cc = o & (side - 1);
    int i = 5 - j;
    int s = 1 << i, p = 1 << (i + 1);
    int r, c;
    if (g == 1)      { r = s + rr * p; c = s + cc * p; }
    else if (g == 2) { r = s + rr * p; c = cc * p;     }
    else             { r = rr * p;     c = s + cc * p; }
    return r * 64 + c;
}

// lattice site s -> folded index n
__device__ __forceinline__ int inv_site(int s) {
    if (s == 0) return 0;
    int r = s >> 6, c = s & 63;
    int ir = r ? __builtin_ctz(r) : 6;
    int ic = c ? __builtin_ctz(c) : 6;
    int i = ir < ic ? ir : ic;
    int j = 5 - i;
    int rb = (r >> i) & 1, cb = (c >> i) & 1;
    int g = rb ? (cb ? 1 : 2) : 3;
    return (g << (2 * j)) + ((r >> (i + 1)) << j) + (c >> (i + 1));
}

// fragment-order element index for activation storage [k][b] (bf16)
__device__ __forceinline__ size_t fidx(int k, int b) {
    return (size_t)(((k >> 5) * 8 + (b >> 4)) * 512 + ((k >> 2) & 3) * 128 +
                    (b & 15) * 8 + ((k >> 4) & 1) * 4 + (k & 3));
}

__device__ __forceinline__ unsigned short f2bf(float f) {
    __hip_bfloat16 h = __float2bfloat16(f);
    return __builtin_bit_cast(unsigned short, h);
}

// fold: xf_frag[n][b] = x[b][site(n)] as bf16, coalesced reads over x
__global__ void fold_k(const float* __restrict__ x, unsigned short* __restrict__ xf) {
    int gid = blockIdx.x * 256 + threadIdx.x;  // b*4096 + s
    int b = gid >> 12, s = gid & 4095;
    float v = x[gid];
    int n = inv_site(s);
    xf[fidx(n, b)] = f2bf(v);
}

// Masked GEMM, register-streaming: out[m][b] = act(sum_k W[m][k]*A[k][b] + bias)
// A: bf16 fragment-order (fidx), W: fp32 row-major [M][Ktot].
// 16 rows per block; 8 waves split K round-robin (64-k steps); LDS reduce at end.
// MODE 0: prelu -> bf16 frag-order store.  MODE 1: sigmoid + unfold scatter -> [B][N] fp32.
template <bool EXCL, int MODE>
__global__ __launch_bounds__(512, 2) void made_gemm2(
        const unsigned short* __restrict__ A, const float* __restrict__ W,
        const float* __restrict__ bias, const float* __restrict__ alpha,
        void* __restrict__ outp, int M, int Ktot, int nseg) {
    __shared__ f32x4 red[8 * 8 * 64];  // [wave][q][lane] = 64 KB

    const int tid  = threadIdx.x;
    const int wid  = tid >> 6;
    const int lane = tid & 63;
    const int r0   = M - 16 - (int)blockIdx.x * 16;   // reversed: heavy tiles first
    const int r_ch = r0 & (NN - 1);
    const int row  = lane & 15;      // W row within tile (A-operand row)
    const int kq   = lane >> 4;      // k-quad within fragment

    int S, E;
    klims(r_ch + row, S, E);
    const int kl = EXCL ? S : E;     // per-row seg-local prefix limit
    klims(r_ch + 15, S, E);
    const int kmax = EXCL ? S : E;   // tile max (monotone in r)
    const int nkt = (kmax + 63) >> 6;
    const int nt  = nseg * nkt;
    const bool uni = (r_ch >= 64);   // uniform group: no element masking needed

    f32x4 acc[8] = {};
    const float* wrow = W + (size_t)(r0 + row) * Ktot + kq * 4;

    for (int t = wid; t < nt; t += 8) {
        int seg = (nseg == 2 && t >= nkt) ? 1 : 0;
        int kb  = (t - seg * nkt) << 6;     // seg-local k base
        int kg  = seg * NN + kb;            // global k base
        const float* wp = wrow + kg;
        float4 w0 = *(const float4*)(wp);
        float4 w1 = *(const float4*)(wp + 16);
        float4 w2 = *(const float4*)(wp + 32);
        float4 w3 = *(const float4*)(wp + 48);
        if (!uni) {
            int k0 = kb + kq * 4;
            w0.x = (k0 +  0 < kl) ? w0.x : 0.0f;
            w0.y = (k0 +  1 < kl) ? w0.y : 0.0f;
            w0.z = (k0 +  2 < kl) ? w0.z : 0.0f;
            w0.w = (k0 +  3 < kl) ? w0.w : 0.0f;
            w1.x = (k0 + 16 < kl) ? w1.x : 0.0f;
            w1.y = (k0 + 17 < kl) ? w1.y : 0.0f;
            w1.z = (k0 + 18 < kl) ? w1.z : 0.0f;
            w1.w = (k0 + 19 < kl) ? w1.w : 0.0f;
            w2.x = (k0 + 32 < kl) ? w2.x : 0.0f;
            w2.y = (k0 + 33 < kl) ? w2.y : 0.0f;
            w2.z = (k0 + 34 < kl) ? w2.z : 0.0f;
            w2.w = (k0 + 35 < kl) ? w2.w : 0.0f;
            w3.x = (k0 + 48 < kl) ? w3.x : 0.0f;
            w3.y = (k0 + 49 < kl) ? w3.y : 0.0f;
            w3.z = (k0 + 50 < kl) ? w3.z : 0.0f;
            w3.w = (k0 + 51 < kl) ? w3.w : 0.0f;
        }
        short8 wf0, wf1;
        wf0[0] = (short)f2bf(w0.x); wf0[1] = (short)f2bf(w0.y);
        wf0[2] = (short)f2bf(w0.z); wf0[3] = (short)f2bf(w0.w);
        wf0[4] = (short)f2bf(w1.x); wf0[5] = (short)f2bf(w1.y);
        wf0[6] = (short)f2bf(w1.z); wf0[7] = (short)f2bf(w1.w);
        wf1[0] = (short)f2bf(w2.x); wf1[1] = (short)f2bf(w2.y);
        wf1[2] = (short)f2bf(w2.z); wf1[3] = (short)f2bf(w2.w);
        wf1[4] = (short)f2bf(w3.x); wf1[5] = (short)f2bf(w3.y);
        wf1[6] = (short)f2bf(w3.z); wf1[7] = (short)f2bf(w3.w);

        const unsigned short* ab = A + (size_t)(kg >> 5) * 4096 + lane * 8;
#pragma unroll
        for (int q = 0; q < 8; ++q) {
            short8 a0 = *(const short8*)(ab + q * 512);
            short8 a1 = *(const short8*)(ab + 4096 + q * 512);
            acc[q] = __builtin_amdgcn_mfma_f32_16x16x32_bf16(wf0, a0, acc[q], 0, 0, 0);
            acc[q] = __builtin_amdgcn_mfma_f32_16x16x32_bf16(wf1, a1, acc[q], 0, 0, 0);
        }
    }

    // cross-wave K reduce (conflict-free f32x4 at lane*16)
#pragma unroll
    for (int q = 0; q < 8; ++q) red[(wid * 8 + q) * 64 + lane] = acc[q];
    __syncthreads();
    const int q = wid;
    f32x4 sum = red[q * 64 + lane];
#pragma unroll
    for (int w = 1; w < 8; ++w) sum += red[(w * 8 + q) * 64 + lane];

    const int m0 = r0 + kq * 4;
    const int b  = q * 16 + row;
    if (MODE == 0) {
        f32x4 bv = *(const f32x4*)&bias[m0];
        f32x4 av = *(const f32x4*)&alpha[m0];
        ushort4 st;
        float v;
        v = sum[0] + bv[0]; v = fmaxf(v, 0.0f) + av[0] * fminf(v, 0.0f); st.x = f2bf(v);
        v = sum[1] + bv[1]; v = fmaxf(v, 0.0f) + av[1] * fminf(v, 0.0f); st.y = f2bf(v);
        v = sum[2] + bv[2]; v = fmaxf(v, 0.0f) + av[2] * fminf(v, 0.0f); st.z = f2bf(v);
        v = sum[3] + bv[3]; v = fmaxf(v, 0.0f) + av[3] * fminf(v, 0.0f); st.w = f2bf(v);
        unsigned short* hout = (unsigned short*)outp;
        *(ushort4*)&hout[fidx(m0, b)] = st;   // 4 consecutive j-slots: one 8B store
    } else {
        float* out = (float*)outp;
        f32x4 bv = *(const f32x4*)&bias[m0];
#pragma unroll
        for (int i = 0; i < 4; ++i) {
            int m = m0 + i;
            float v = sum[i] + bv[i];
            float sg = 1.0f / (1.0f + __expf(-v));
            if (m == 0) sg = 0.5f;
            out[(size_t)b * NN + perm_site(m)] = sg;
        }
    }
}

extern "C" void kernel_launch(void* const* d_in, const int* in_sizes, int n_in,
                              void* d_out, int out_size, void* d_ws, size_t ws_size,
                              hipStream_t stream) {
    const float* x  = (const float*)d_in[0];
    const float* W0 = (const float*)d_in[1];
    const float* b0 = (const float*)d_in[2];
    const float* a1 = (const float*)d_in[3];
    const float* W1 = (const float*)d_in[4];
    const float* b1 = (const float*)d_in[5];
    const float* a2 = (const float*)d_in[6];
    const float* W2 = (const float*)d_in[7];
    const float* b2 = (const float*)d_in[8];

    char* ws = (char*)d_ws;
    unsigned short* xf = (unsigned short*)ws;                // 1 MB  (4096x128 bf16, frag order)
    unsigned short* h0 = (unsigned short*)(ws + (1 << 20));  // 2 MB  (8192x128)
    unsigned short* h1 = (unsigned short*)(ws + (3 << 20));  // 2 MB  (8192x128)

    fold_k<<<2048, 256, 0, stream>>>(x, xf);
    made_gemm2<true, 0><<<512, 512, 0, stream>>>(xf, W0, b0, a1, h0, 2 * NN, NN, 1);
    made_gemm2<false, 0><<<512, 512, 0, stream>>>(h0, W1, b1, a2, h1, 2 * NN, 2 * NN, 2);
    made_gemm2<false, 1><<<256, 512, 0, stream>>>(h1, W2, b2, nullptr, (float*)d_out, NN, 2 * NN, 2);
}